// Round 14
// baseline (319.850 us; speedup 1.0000x reference)
//
#include <hip/hip_runtime.h>
#include <hip/hip_bf16.h>

#define N_NODES 10000
#define N_PAD   10016
#define E_EDGES 160000
#define EB 32
#define EB2 64
#define NTILES (E_EDGES / EB)
#define HID 256

typedef __attribute__((ext_vector_type(4))) float f32x4;
typedef __attribute__((ext_vector_type(8))) short bf16x8;
typedef __attribute__((ext_vector_type(8))) unsigned short u16x8;
typedef __attribute__((ext_vector_type(4))) unsigned u32x4;
typedef unsigned short u16;
typedef __attribute__((address_space(1))) const unsigned int gu32;
typedef __attribute__((address_space(3))) unsigned int lu32;

__device__ __forceinline__ float silu_f(float x) { return x / (1.0f + __expf(-x)); }

__device__ __forceinline__ u16 f2bf(float f) {           // round-to-nearest-even
    unsigned x = __float_as_uint(f);
    unsigned r = x + 0x7FFFu + ((x >> 16) & 1u);
    return (u16)(r >> 16);
}
__device__ __forceinline__ float bf2f(u16 u) {
    return __uint_as_float(((unsigned)u) << 16);
}
__device__ __forceinline__ unsigned cvtpk(float a, float b) {
    unsigned r;
    asm("v_cvt_pk_bf16_f32 %0, %1, %2" : "=v"(r) : "v"(a), "v"(b));
    return r;
}
__device__ __forceinline__ f32x4 mfma16(bf16x8 a, bf16x8 b, f32x4 c) {
    return __builtin_amdgcn_mfma_f32_16x16x32_bf16(a, b, c, 0, 0, 0);
}
// swizzled byte offset into a [rows][256] u16 activation tile (stride 512B)
__device__ __forceinline__ int actb(int row, int elem) {
    return (row * 512 + elem * 2) ^ ((row & 7) << 4);
}
// bijective XCD-chunked swizzle (m204)
__device__ __forceinline__ int xcd_swz(int bid, int nwg) {
    int qq = nwg >> 3, r8 = nwg & 7;
    int xcd = bid & 7, sub = bid >> 3;
    return (xcd < r8 ? xcd * (qq + 1) : r8 * (qq + 1) + (xcd - r8) * qq) + sub;
}

// ---------------------------------------------------------------------------
// prep: y=0..5 plain [n][k] bf16 transposes; y=6,7 chunked per-lane-read-order
// B images (e2s = eW2, c1s = cW1).
// ---------------------------------------------------------------------------
__global__ __launch_bounds__(256) void prep_weights(
    const float* __restrict__ eW1, const float* __restrict__ eW2,
    const float* __restrict__ cW1, const float* __restrict__ nW1,
    const float* __restrict__ nW2,
    u16* __restrict__ Wt3, u16* __restrict__ e1pt,
    u16* __restrict__ n1t, u16* __restrict__ n2t,
    u16* __restrict__ e2s, u16* __restrict__ c1s)
{
    const int y = blockIdx.y;
    if (y >= 6) {                 // chunked B images
        if (blockIdx.x >= 32) return;
        const float* W = (y == 6) ? eW2 : cW1;
        u16* dst = (y == 6) ? e2s : c1s;
        int T = blockIdx.x * 256 + threadIdx.x;      // [0, 8192)
        int kc = T >> 10, rem = T & 1023;
        int q = rem >> 6, lane = rem & 63;
        int n = (q >> 2) * 64 + (q & 3) * 16 + (lane & 15);
        int kbase = kc * 32 + (lane >> 4) * 8;
        u16x8 o;
#pragma unroll
        for (int jj = 0; jj < 8; ++jj)
            o[jj] = f2bf(W[(size_t)(kbase + jj) * 256 + n]);
        *(u16x8*)&dst[(size_t)T * 8] = o;
        return;
    }
    const float* src; u16* dstp; int Ks, Kd;
    switch (y) {
        case 0: src = eW1;                dstp = Wt3;                Ks = 512; Kd = 512; break;
        case 1: src = eW1 + 512 * 256;    dstp = Wt3 + 256 * 512;    Ks = 512; Kd = 512; break;
        case 2: src = nW1;                dstp = Wt3 + 2 * 256 * 512; Ks = 512; Kd = 512; break;
        case 3: src = eW1 + 1024 * 256;   dstp = e1pt;               Ks = 52;  Kd = 64;  break;
        case 4: src = nW1 + 512 * 256;    dstp = n1t;                Ks = 256; Kd = 256; break;
        default: src = nW2;               dstp = n2t;                Ks = 256; Kd = 256; break;
    }
    int idx = blockIdx.x * 256 + threadIdx.x;
    if (idx < 256 * Kd) {
        int n = idx / Kd, k = idx - n * Kd;
        dstp[idx] = (k < Ks) ? f2bf(src[(size_t)k * 256 + n]) : (u16)0;
    }
}

__global__ __launch_bounds__(256) void conv_h(const float* __restrict__ h, u16* __restrict__ hb)
{
    size_t base = ((size_t)blockIdx.x * 256 + threadIdx.x) * 8;
    int row = (int)(base >> 9);
    u16x8 o;
    if (row < N_NODES) {
        const float4 f0 = *(const float4*)&h[base];
        const float4 f1 = *(const float4*)&h[base + 4];
        o[0] = f2bf(f0.x); o[1] = f2bf(f0.y); o[2] = f2bf(f0.z); o[3] = f2bf(f0.w);
        o[4] = f2bf(f1.x); o[5] = f2bf(f1.y); o[6] = f2bf(f1.z); o[7] = f2bf(f1.w);
    } else {
        o = (u16x8)0;
    }
    *(u16x8*)&hb[base] = o;
}

// ---------------------------------------------------------------------------
__global__ __launch_bounds__(256) void hist_kernel(const int* __restrict__ row,
                                                   int* __restrict__ hist)
{
    int e = blockIdx.x * 256 + threadIdx.x;
    if (e < E_EDGES) atomicAdd(&hist[row[e]], 1);
}

#define SCAN_PER 40
__global__ __launch_bounds__(256) void scan_kernel(const int* __restrict__ hist,
                                                   int* __restrict__ rowptr)
{
    __shared__ int a[256];
    const int t = threadIdx.x;
    const int base = t * SCAN_PER;
    int s = 0;
    for (int i = 0; i < SCAN_PER; ++i) {
        int b = base + i;
        if (b < N_PAD) s += hist[b];
    }
    a[t] = s;
    __syncthreads();
    for (int off = 1; off < 256; off <<= 1) {
        int v = (t >= off) ? a[t - off] : 0;
        __syncthreads();
        a[t] += v;
        __syncthreads();
    }
    int run = a[t] - s;
    for (int i = 0; i < SCAN_PER; ++i) {
        int b = base + i;
        if (b < N_PAD) { rowptr[b] = run; run += hist[b]; }
    }
    if (t == 255) rowptr[N_PAD] = a[255];
}

__global__ __launch_bounds__(256) void scatter_kernel(const int* __restrict__ row,
                                                      const int* __restrict__ rowptr,
                                                      int* __restrict__ cnt,
                                                      int* __restrict__ eorder)
{
    int e = blockIdx.x * 256 + threadIdx.x;
    if (e < E_EDGES) {
        int r = row[e];
        int p = rowptr[r] + atomicAdd(&cnt[r], 1);
        eorder[p] = e;
    }
}

// ---------------------------------------------------------------------------
__global__ __launch_bounds__(256) void precompute_X(
    const u16* __restrict__ hb, const u16* __restrict__ Wt3, u16* __restrict__ Xb)
{
    const int n0b = blockIdx.x * 32;
    const int which = blockIdx.y;
    const int j = threadIdx.x, wv = j >> 6, lane = j & 63;
    const int ml = lane & 15, g = lane >> 4;
    const int n0 = wv * 64;
    const u16* W = Wt3 + (size_t)which * 256 * 512;

    f32x4 acc[2][4];
    const f32x4 z = {0.f, 0.f, 0.f, 0.f};
#pragma unroll
    for (int mt = 0; mt < 2; ++mt)
#pragma unroll
        for (int nt = 0; nt < 4; ++nt) acc[mt][nt] = z;

    for (int kc = 0; kc < 16; ++kc) {
        bf16x8 a0 = *(const bf16x8*)&hb[(size_t)(n0b + ml) * 512 + kc * 32 + g * 8];
        bf16x8 a1 = *(const bf16x8*)&hb[(size_t)(n0b + 16 + ml) * 512 + kc * 32 + g * 8];
#pragma unroll
        for (int nt = 0; nt < 4; ++nt) {
            bf16x8 b = *(const bf16x8*)&W[(size_t)(n0 + nt * 16 + ml) * 512 + kc * 32 + g * 8];
            acc[0][nt] = mfma16(a0, b, acc[0][nt]);
            acc[1][nt] = mfma16(a1, b, acc[1][nt]);
        }
    }
#pragma unroll
    for (int mt = 0; mt < 2; ++mt)
#pragma unroll
        for (int nt = 0; nt < 4; ++nt) {
            int col = n0 + nt * 16 + ml;
#pragma unroll
            for (int i = 0; i < 4; ++i) {
                int row = n0b + mt * 16 + g * 4 + i;
                Xb[(size_t)row * 768 + which * 256 + col] = f2bf(acc[mt][nt][i]);
            }
        }
}

// ---------------------------------------------------------------------------
// e1: gather + attr + stage-1 MFMA -> act1 tiles in HBM (swizzled tile image)
// ---------------------------------------------------------------------------
__global__ __launch_bounds__(256) void e1_kernel(
    const u16* __restrict__ Xb, const float* __restrict__ pos,
    const int* __restrict__ eidx, const float* __restrict__ eattr,
    const int* __restrict__ eorder,
    const u16* __restrict__ e1pt, const float* __restrict__ eb1,
    int t0, u16* __restrict__ act1s,
    int* __restrict__ ri_sorted, float* __restrict__ difp)
{
    __shared__ u16 attr[EB * 64];     // 4 KB swizzled
    __shared__ u16 bufA[EB * 256];    // 16 KB, xsum -> act1 in place
    __shared__ int ri_s[EB], ci_s[EB], es_s[EB];
    __shared__ float rad_s[EB];

    const int j = threadIdx.x, w = j >> 6, lane = j & 63;
    const int ml = lane & 15, g = lane >> 4;
    const int n0 = w * 64;
    const f32x4 z = {0.f, 0.f, 0.f, 0.f};

    const int wg = xcd_swz(blockIdx.x, gridDim.x);
    const int e0 = (t0 + wg) * EB;

    if (j < EB) {
        int e = eorder[e0 + j];
        es_s[j] = e;
        int r = eidx[e], c = eidx[E_EDGES + e];
        ri_s[j] = r; ci_s[j] = c;
        ri_sorted[e0 + j] = r;
        float dx = pos[r * 3 + 0] - pos[c * 3 + 0];
        float dy = pos[r * 3 + 1] - pos[c * 3 + 1];
        float dz = pos[r * 3 + 2] - pos[c * 3 + 2];
        difp[e0 + j] = dx;
        difp[E_EDGES + e0 + j] = dy;
        difp[2 * E_EDGES + e0 + j] = dz;
        rad_s[j] = sqrtf(dx * dx + dy * dy + dz * dz) + 1e-8f;
    }
    __syncthreads();

    // gather xsum = Xr + Xc -> bufA (swizzled)
#pragma unroll
    for (int t = 0; t < 4; ++t) {
        int li = t * 256 + j;
        int e = li >> 5, c = li & 31;
        const u16x8 xr = *(const u16x8*)&Xb[(size_t)ri_s[e] * 768 + c * 8];
        const u16x8 xc = *(const u16x8*)&Xb[(size_t)ci_s[e] * 768 + 256 + c * 8];
        u32x4 o;
#pragma unroll
        for (int k = 0; k < 4; ++k)
            o[k] = cvtpk(bf2f(xr[2 * k]) + bf2f(xc[2 * k]),
                         bf2f(xr[2 * k + 1]) + bf2f(xc[2 * k + 1]));
        *(u32x4*)((char*)bufA + ((e * 512 + c * 16) ^ ((e & 7) << 4))) = o;
    }
    // attr staging (+radial col 51)
    for (int li = j; li < EB * 64; li += 256) {
        int row = li >> 6, k = li & 63;
        float v = (k < 51) ? eattr[(size_t)es_s[row] * 51 + k] : (k == 51 ? rad_s[row] : 0.f);
        int byte = (row * 128 + k * 2) ^ ((row & 7) << 4);
        attr[byte >> 1] = f2bf(v);
    }
    __syncthreads();

    f32x4 acc[2][4];
#pragma unroll
    for (int mt = 0; mt < 2; ++mt)
#pragma unroll
        for (int nt = 0; nt < 4; ++nt) acc[mt][nt] = z;
#pragma unroll
    for (int kc = 0; kc < 2; ++kc) {
        bf16x8 a0 = *(const bf16x8*)((const char*)attr + ((ml * 128 + (kc * 32 + g * 8) * 2) ^ ((ml & 7) << 4)));
        bf16x8 a1 = *(const bf16x8*)((const char*)attr + (((16 + ml) * 128 + (kc * 32 + g * 8) * 2) ^ ((ml & 7) << 4)));
#pragma unroll
        for (int nt = 0; nt < 4; ++nt) {
            bf16x8 b = *(const bf16x8*)&e1pt[(size_t)(n0 + nt * 16 + ml) * 64 + kc * 32 + g * 8];
            acc[0][nt] = mfma16(a0, b, acc[0][nt]);
            acc[1][nt] = mfma16(a1, b, acc[1][nt]);
        }
    }
#pragma unroll
    for (int nt = 0; nt < 4; ++nt) {
        int col = n0 + nt * 16 + ml;
        float b1 = eb1[col];
#pragma unroll
        for (int mt = 0; mt < 2; ++mt)
#pragma unroll
            for (int i = 0; i < 4; ++i) {
                int row = mt * 16 + g * 4 + i;
                int off = actb(row, col) >> 1;
                float v = acc[mt][nt][i] + b1 + bf2f(bufA[off]);
                bufA[off] = f2bf(silu_f(v));
            }
    }
    __syncthreads();

    // coalesced copy of swizzled tile image to HBM
    const size_t obase = (size_t)wg * (EB * 256);
#pragma unroll
    for (int i = 0; i < 4; ++i) {
        int li = i * 256 + j;
        *(u16x8*)&act1s[obase + (size_t)li * 8] = *(const u16x8*)&bufA[li * 8];
    }
}

// ---------------------------------------------------------------------------
// e2 v4: EB2=64 edges/block (two act1 images), acc[4][4]. Wave-private
// half-chunk B double-buffer, counted vmcnt, zero barriers in K-loops.
// ---------------------------------------------------------------------------
__global__ __launch_bounds__(256) void e2_kernel(
    const u16* __restrict__ act1s,
    const u16* __restrict__ e2s, const float* __restrict__ eb2,
    const u16* __restrict__ c1s, const float* __restrict__ cb1,
    const float* __restrict__ cW2,
    const int* __restrict__ ri_sorted, const float* __restrict__ difp,
    int t0, float* __restrict__ agg_node, float* __restrict__ agg_coord)
{
    __shared__ u16 bufA[EB2 * 256];   // 32 KB act1 -> act2 in place
    __shared__ u16 ldsB[2][4096];     // 16 KB half-chunk double buffer
    __shared__ int ri_s[EB2];
    __shared__ float red[EB2 * 4];

    const int j = threadIdx.x, w = j >> 6, lane = j & 63;
    const int ml = lane & 15, g = lane >> 4;
    const int n0 = w * 64;
    const f32x4 z = {0.f, 0.f, 0.f, 0.f};

    const int wgp = xcd_swz(blockIdx.x, gridDim.x);
    const int e0 = t0 * EB + wgp * EB2;         // absolute edge base (t0 even)

    // stage both act tile images (linear; pre-swizzled) + e2s half-chunk 0
    {
        const size_t gbase = (size_t)wgp * (EB2 * 256);
#pragma unroll
        for (int i = 0; i < 8; ++i) {
            const u16* src = act1s + gbase + (size_t)(i * 256 + j) * 8;
            u16* dst = &bufA[(i * 256 + j) * 8];
            __builtin_amdgcn_global_load_lds((gu32*)src, (lu32*)dst, 16, 0, 0);
        }
#pragma unroll
        for (int i = 0; i < 2; ++i) {
            const u16* src = e2s + (size_t)((4 * w + i) * 512 + lane * 8);
            u16* dst = &ldsB[0][w * 1024 + i * 512 + lane * 8];
            __builtin_amdgcn_global_load_lds((gu32*)src, (lu32*)dst, 16, 0, 0);
        }
    }
    if (j < EB2) ri_s[j] = ri_sorted[e0 + j];
    // act tiles (oldest 8 loads) complete; chunk-0 may stay in flight
    asm volatile("s_waitcnt vmcnt(2) lgkmcnt(0)" ::: "memory");
    __builtin_amdgcn_s_barrier();

    f32x4 acc[4][4];

    // ---- stage 2: barrier-free K-loop, 16 half-chunks, counted vmcnt
#pragma unroll
    for (int mt = 0; mt < 4; ++mt)
#pragma unroll
        for (int nt = 0; nt < 4; ++nt) acc[mt][nt] = z;
    for (int hc = 0; hc < 16; ++hc) {
        int kc = hc >> 1, h = hc & 1;
        if (hc < 15) {
            int kc1 = (hc + 1) >> 1, h1 = (hc + 1) & 1;
#pragma unroll
            for (int i = 0; i < 2; ++i) {
                const u16* src = e2s + (size_t)kc1 * 8192 + (4 * w + 2 * h1 + i) * 512 + lane * 8;
                u16* dst = &ldsB[(hc + 1) & 1][w * 1024 + i * 512 + lane * 8];
                __builtin_amdgcn_global_load_lds((gu32*)src, (lu32*)dst, 16, 0, 0);
            }
            asm volatile("s_waitcnt vmcnt(2)" ::: "memory");
        } else {
            asm volatile("s_waitcnt vmcnt(0)" ::: "memory");
        }
        __builtin_amdgcn_sched_barrier(0);
        bf16x8 a[4];
#pragma unroll
        for (int mt = 0; mt < 4; ++mt)
            a[mt] = *(const bf16x8*)((const char*)bufA + actb(mt * 16 + ml, kc * 32 + g * 8));
#pragma unroll
        for (int i = 0; i < 2; ++i) {
            int nt = 2 * h + i;
            bf16x8 b = *(const bf16x8*)&ldsB[hc & 1][w * 1024 + i * 512 + lane * 8];
#pragma unroll
            for (int mt = 0; mt < 4; ++mt)
                acc[mt][nt] = mfma16(a[mt], b, acc[mt][nt]);
        }
    }
    asm volatile("s_waitcnt lgkmcnt(0)" ::: "memory");
    __builtin_amdgcn_s_barrier();                 // all act1 reads done

    // prefetch c1s half-chunk 0 (overlaps epilogue)
#pragma unroll
    for (int i = 0; i < 2; ++i) {
        const u16* src = c1s + (size_t)((4 * w + i) * 512 + lane * 8);
        u16* dst = &ldsB[0][w * 1024 + i * 512 + lane * 8];
        __builtin_amdgcn_global_load_lds((gu32*)src, (lu32*)dst, 16, 0, 0);
    }

    // stage-2 epilogue: act2 = silu(acc + b2) in place
#pragma unroll
    for (int nt = 0; nt < 4; ++nt) {
        int col = n0 + nt * 16 + ml;
        float b2 = eb2[col];
#pragma unroll
        for (int mt = 0; mt < 4; ++mt)
#pragma unroll
            for (int i = 0; i < 4; ++i) {
                int row = mt * 16 + g * 4 + i;
                bufA[actb(row, col) >> 1] = f2bf(silu_f(acc[mt][nt][i] + b2));
            }
    }
    asm volatile("s_waitcnt lgkmcnt(0)" ::: "memory");
    __builtin_amdgcn_s_barrier();                 // act2 visible

    // ---- stage 3: same barrier-free K-loop with c1s
#pragma unroll
    for (int mt = 0; mt < 4; ++mt)
#pragma unroll
        for (int nt = 0; nt < 4; ++nt) acc[mt][nt] = z;
    for (int hc = 0; hc < 16; ++hc) {
        int kc = hc >> 1, h = hc & 1;
        if (hc < 15) {
            int kc1 = (hc + 1) >> 1, h1 = (hc + 1) & 1;
#pragma unroll
            for (int i = 0; i < 2; ++i) {
                const u16* src = c1s + (size_t)kc1 * 8192 + (4 * w + 2 * h1 + i) * 512 + lane * 8;
                u16* dst = &ldsB[(hc + 1) & 1][w * 1024 + i * 512 + lane * 8];
                __builtin_amdgcn_global_load_lds((gu32*)src, (lu32*)dst, 16, 0, 0);
            }
            asm volatile("s_waitcnt vmcnt(2)" ::: "memory");
        } else {
            asm volatile("s_waitcnt vmcnt(0)" ::: "memory");
        }
        __builtin_amdgcn_sched_barrier(0);
        bf16x8 a[4];
#pragma unroll
        for (int mt = 0; mt < 4; ++mt)
            a[mt] = *(const bf16x8*)((const char*)bufA + actb(mt * 16 + ml, kc * 32 + g * 8));
#pragma unroll
        for (int i = 0; i < 2; ++i) {
            int nt = 2 * h + i;
            bf16x8 b = *(const bf16x8*)&ldsB[hc & 1][w * 1024 + i * 512 + lane * 8];
#pragma unroll
            for (int mt = 0; mt < 4; ++mt)
                acc[mt][nt] = mfma16(a[mt], b, acc[mt][nt]);
        }
    }

    // ---- p-epilogue first (consumes acc): u = clip((silu(c + cb1)) . cW2)
    float p[4][4];
#pragma unroll
    for (int mt = 0; mt < 4; ++mt)
#pragma unroll
        for (int i = 0; i < 4; ++i) p[mt][i] = 0.f;
#pragma unroll
    for (int nt = 0; nt < 4; ++nt) {
        int col = n0 + nt * 16 + ml;
        float b3 = cb1[col];
        float w2 = cW2[col];
#pragma unroll
        for (int mt = 0; mt < 4; ++mt)
#pragma unroll
            for (int i = 0; i < 4; ++i)
                p[mt][i] += silu_f(acc[mt][nt][i] + b3) * w2;
    }
#pragma unroll
    for (int mt = 0; mt < 4; ++mt)
#pragma unroll
        for (int i = 0; i < 4; ++i) {
            float v = p[mt][i];
            v += __shfl_xor(v, 1);
            v += __shfl_xor(v, 2);
            v += __shfl_xor(v, 4);
            v += __shfl_xor(v, 8);
            p[mt][i] = v;
        }
    if (ml == 0) {
#pragma unroll
        for (int mt = 0; mt < 4; ++mt)
#pragma unroll
            for (int i = 0; i < 4; ++i)
                red[(mt * 16 + g * 4 + i) * 4 + w] = p[mt][i];
    }
    __syncthreads();
    if (j < EB2) {
        float u = red[j * 4 + 0] + red[j * 4 + 1] + red[j * 4 + 2] + red[j * 4 + 3];
        u = fminf(fmaxf(u, -1.f), 1.f);
        int rr = ri_s[j];
        atomicAdd(&agg_coord[(size_t)rr * 3 + 0], u * difp[e0 + j]);
        atomicAdd(&agg_coord[(size_t)rr * 3 + 1], u * difp[E_EDGES + e0 + j]);
        atomicAdd(&agg_coord[(size_t)rr * 3 + 2], u * difp[2 * E_EDGES + e0 + j]);
    }

    // ---- RL-agg in two 32-row halves with carry (<=32 live vregs)
    {
        int cur = ri_s[0];
        float s = 0.f;
#pragma unroll
        for (int half = 0; half < 2; ++half) {
            float vreg[32];
#pragma unroll
            for (int m = 0; m < 32; ++m)
                vreg[m] = bf2f(bufA[actb(half * 32 + m, j) >> 1]);
#pragma unroll
            for (int m = 0; m < 32; ++m) {
                int r = ri_s[half * 32 + m];
                if (r != cur) {
                    atomicAdd(&agg_node[(size_t)cur * 256 + j], s);
                    s = 0.f; cur = r;
                }
                s += vreg[m];
            }
        }
        atomicAdd(&agg_node[(size_t)cur * 256 + j], s);
    }
}

// ---------------------------------------------------------------------------
__global__ __launch_bounds__(256) void node_kernel(
    const u16* __restrict__ Xb, const float* __restrict__ agg_node,
    const float* __restrict__ agg_coord, const float* __restrict__ pos,
    const u16* __restrict__ n1t, const float* __restrict__ nb1,
    const u16* __restrict__ n2t, const float* __restrict__ nb2,
    float* __restrict__ out)
{
    __shared__ u16 act1[32 * 256];
    __shared__ u16 act2[32 * 256];
    const int n0b = blockIdx.x * 32;
    const int j = threadIdx.x, wv = j >> 6, lane = j & 63;
    const int ml = lane & 15, g = lane >> 4;
    const int n0 = wv * 64;
    const f32x4 z = {0.f, 0.f, 0.f, 0.f};

    for (int li = j; li < 32 * 256; li += 256) {
        int r = li >> 8, c = li & 255;
        act1[actb(r, c) >> 1] = f2bf(agg_node[(size_t)(n0b + r) * 256 + c]);
    }
    __syncthreads();

    f32x4 acc[2][4];
#pragma unroll
    for (int mt = 0; mt < 2; ++mt)
#pragma unroll
        for (int nt = 0; nt < 4; ++nt) acc[mt][nt] = z;
    for (int kc = 0; kc < 8; ++kc) {
        bf16x8 a0 = *(const bf16x8*)((const char*)act1 + actb(ml, kc * 32 + g * 8));
        bf16x8 a1 = *(const bf16x8*)((const char*)act1 + actb(16 + ml, kc * 32 + g * 8));
#pragma unroll
        for (int nt = 0; nt < 4; ++nt) {
            bf16x8 b = *(const bf16x8*)&n1t[(size_t)(n0 + nt * 16 + ml) * 256 + kc * 32 + g * 8];
            acc[0][nt] = mfma16(a0, b, acc[0][nt]);
            acc[1][nt] = mfma16(a1, b, acc[1][nt]);
        }
    }
#pragma unroll
    for (int mt = 0; mt < 2; ++mt)
#pragma unroll
        for (int nt = 0; nt < 4; ++nt) {
            int col = n0 + nt * 16 + ml;
            float b1 = nb1[col];
#pragma unroll
            for (int i = 0; i < 4; ++i) {
                int m = mt * 16 + g * 4 + i;
                float v = acc[mt][nt][i] + b1 + bf2f(Xb[(size_t)(n0b + m) * 768 + 512 + col]);
                act2[actb(m, col) >> 1] = f2bf(silu_f(v));
            }
        }
    __syncthreads();
#pragma unroll
    for (int mt = 0; mt < 2; ++mt)
#pragma unroll
        for (int nt = 0; nt < 4; ++nt) acc[mt][nt] = z;
    for (int kc = 0; kc < 8; ++kc) {
        bf16x8 a0 = *(const bf16x8*)((const char*)act2 + actb(ml, kc * 32 + g * 8));
        bf16x8 a1 = *(const bf16x8*)((const char*)act2 + actb(16 + ml, kc * 32 + g * 8));
#pragma unroll
        for (int nt = 0; nt < 4; ++nt) {
            bf16x8 b = *(const bf16x8*)&n2t[(size_t)(n0 + nt * 16 + ml) * 256 + kc * 32 + g * 8];
            acc[0][nt] = mfma16(a0, b, acc[0][nt]);
            acc[1][nt] = mfma16(a1, b, acc[1][nt]);
        }
    }
#pragma unroll
    for (int mt = 0; mt < 2; ++mt)
#pragma unroll
        for (int nt = 0; nt < 4; ++nt) {
            int col = n0 + nt * 16 + ml;
            float b2 = nb2[col];
#pragma unroll
            for (int i = 0; i < 4; ++i) {
                int row = n0b + mt * 16 + g * 4 + i;
                if (row < N_NODES)
                    out[(size_t)row * 256 + col] = acc[mt][nt][i] + b2;
            }
        }
    if (j < 96) {
        int idx = n0b * 3 + j;
        if (idx < N_NODES * 3)
            out[(size_t)N_NODES * 256 + idx] = pos[idx] + agg_coord[idx];
    }
}

// ---------------------------------------------------------------------------
extern "C" void kernel_launch(void* const* d_in, const int* in_sizes, int n_in,
                              void* d_out, int out_size, void* d_ws, size_t ws_size,
                              hipStream_t stream)
{
    (void)in_sizes; (void)n_in; (void)out_size;
    const float* h     = (const float*)d_in[0];
    const int*   eidx  = (const int*)d_in[1];
    const float* eattr = (const float*)d_in[2];
    const float* pos   = (const float*)d_in[3];
    const float* eW1   = (const float*)d_in[4];
    const float* eb1   = (const float*)d_in[5];
    const float* eW2   = (const float*)d_in[6];
    const float* eb2   = (const float*)d_in[7];
    const float* cW1   = (const float*)d_in[8];
    const float* cb1   = (const float*)d_in[9];
    const float* cW2   = (const float*)d_in[10];
    const float* nW1   = (const float*)d_in[11];
    const float* nb1   = (const float*)d_in[12];
    const float* nW2   = (const float*)d_in[13];
    const float* nb2   = (const float*)d_in[14];
    float* out = (float*)d_out;

    u16* Xb   = (u16*)d_ws;                                  // N_PAD*768 bf16
    u16* hb   = Xb + (size_t)N_PAD * 768;                    // N_PAD*512
    u16* Wt3  = hb + (size_t)N_PAD * 512;                    // 3*256*512
    u16* e1pt = Wt3 + 3 * 256 * 512;                         // 256*64
    u16* n1t  = e1pt + 256 * 64;                             // 256*256
    u16* n2t  = n1t + 256 * 256;                             // 256*256
    u16* e2s  = n2t + 256 * 256;                             // 65536 u16
    u16* c1s  = e2s + 65536;                                 // 65536 u16
    float* agg_node  = (float*)(c1s + 65536);                // N_PAD*256 f32
    float* agg_coord = agg_node + (size_t)N_PAD * 256;       // N_PAD*3
    int* hist   = (int*)(agg_coord + (size_t)N_PAD * 3);     // N_PAD
    int* cnt    = hist + N_PAD;                              // N_PAD
    int* rowptr = cnt + N_PAD;                               // N_PAD+1
    int* eorder = rowptr + N_PAD + 1;                        // E
    int* ri_sorted = eorder + E_EDGES;                       // E
    float* difp = (float*)(ri_sorted + E_EDGES);             // 3*E
    char* wend = (char*)(difp + (size_t)3 * E_EDGES);
    u16* act1s = (u16*)(((uintptr_t)wend + 255) & ~(uintptr_t)255);

    size_t avail = ws_size - (size_t)((char*)act1s - (char*)d_ws);
    int tiles_cap = (int)(avail / (EB * 256 * sizeof(u16)));
    int chunk = tiles_cap < NTILES ? tiles_cap : NTILES;
    chunk &= ~1;                       // keep e2 pairs aligned
    if (chunk < 2) chunk = 2;

    hipMemsetAsync(agg_node, 0, (size_t)N_PAD * 259 * sizeof(float), stream);
    hipMemsetAsync(hist, 0, (size_t)2 * N_PAD * sizeof(int), stream);

    prep_weights<<<dim3(512, 8), 256, 0, stream>>>(eW1, eW2, cW1, nW1, nW2,
                                                   Wt3, e1pt, n1t, n2t, e2s, c1s);
    conv_h<<<(N_PAD * 512 / 8) / 256, 256, 0, stream>>>(h, hb);

    hist_kernel<<<(E_EDGES + 255) / 256, 256, 0, stream>>>(eidx, hist);
    scan_kernel<<<1, 256, 0, stream>>>(hist, rowptr);
    scatter_kernel<<<(E_EDGES + 255) / 256, 256, 0, stream>>>(eidx, rowptr, cnt, eorder);

    precompute_X<<<dim3(N_PAD / 32, 3), 256, 0, stream>>>(hb, Wt3, Xb);

    for (int c = 0; c < NTILES; c += chunk) {
        int g = (NTILES - c) < chunk ? (NTILES - c) : chunk;
        e1_kernel<<<g, 256, 0, stream>>>(Xb, pos, eidx, eattr, eorder,
                                         e1pt, eb1, c, act1s, ri_sorted, difp);
        e2_kernel<<<g / 2, 256, 0, stream>>>(act1s, e2s, eb2, c1s, cb1, cW2,
                                             ri_sorted, difp, c, agg_node, agg_coord);
    }

    node_kernel<<<N_PAD / 32, 256, 0, stream>>>(
        Xb, agg_node, agg_coord, pos, n1t, nb1, n2t, nb2, out);
}

// Round 15
// 291.016 us; speedup vs baseline: 1.0991x; 1.0991x over previous
//
#include <hip/hip_runtime.h>
#include <hip/hip_bf16.h>

#define N_NODES 10000
#define N_PAD   10016
#define E_EDGES 160000
#define EB 32
#define NTILES (E_EDGES / EB)
#define HID 256

typedef __attribute__((ext_vector_type(4))) float f32x4;
typedef __attribute__((ext_vector_type(8))) short bf16x8;
typedef __attribute__((ext_vector_type(8))) unsigned short u16x8;
typedef __attribute__((ext_vector_type(4))) unsigned u32x4;
typedef unsigned short u16;
typedef __attribute__((address_space(1))) const unsigned int gu32;
typedef __attribute__((address_space(3))) unsigned int lu32;

__device__ __forceinline__ float silu_f(float x) { return x / (1.0f + __expf(-x)); }

__device__ __forceinline__ u16 f2bf(float f) {           // round-to-nearest-even
    unsigned x = __float_as_uint(f);
    unsigned r = x + 0x7FFFu + ((x >> 16) & 1u);
    return (u16)(r >> 16);
}
__device__ __forceinline__ float bf2f(u16 u) {
    return __uint_as_float(((unsigned)u) << 16);
}
__device__ __forceinline__ unsigned cvtpk(float a, float b) {
    unsigned r;
    asm("v_cvt_pk_bf16_f32 %0, %1, %2" : "=v"(r) : "v"(a), "v"(b));
    return r;
}
__device__ __forceinline__ f32x4 mfma16(bf16x8 a, bf16x8 b, f32x4 c) {
    return __builtin_amdgcn_mfma_f32_16x16x32_bf16(a, b, c, 0, 0, 0);
}
// swizzled byte offset into a [rows][256] u16 activation tile (stride 512B)
__device__ __forceinline__ int actb(int row, int elem) {
    return (row * 512 + elem * 2) ^ ((row & 7) << 4);
}
// bijective XCD-chunked swizzle (m204)
__device__ __forceinline__ int xcd_swz(int bid, int nwg) {
    int qq = nwg >> 3, r8 = nwg & 7;
    int xcd = bid & 7, sub = bid >> 3;
    return (xcd < r8 ? xcd * (qq + 1) : r8 * (qq + 1) + (xcd - r8) * qq) + sub;
}

// ---------------------------------------------------------------------------
// prep: y=0 e1pt [n][k64]; y=1 n1t; y=2 n2t ([n][k] bf16);
// y=3 e2s, y=4 c1s (chunked per-lane-read-order, K=256 -> 8 chunks);
// y=5 w3c (3 matrices of eW1[:512],eW1[512:],nW1[:512], K=512 -> 16 chunks).
// chunk layout: u16x8 at T = kc*1024 + q*64 + lane holds W[k][n],
//   n=(q>>2)*64+(q&3)*16+(lane&15), k=kc*32+(lane>>4)*8+jj.
// ---------------------------------------------------------------------------
__global__ __launch_bounds__(256) void prep_weights(
    const float* __restrict__ eW1, const float* __restrict__ eW2,
    const float* __restrict__ cW1, const float* __restrict__ nW1,
    const float* __restrict__ nW2,
    u16* __restrict__ e1pt, u16* __restrict__ n1t, u16* __restrict__ n2t,
    u16* __restrict__ e2s, u16* __restrict__ c1s, u16* __restrict__ w3c)
{
    const int y = blockIdx.y;
    if (y == 5) {                 // w3c: 3 x 16 chunks x 8192 u16
        if (blockIdx.x >= 192) return;
        int T = blockIdx.x * 256 + threadIdx.x;      // [0, 49152)
        int which = T >> 14, rem = T & 16383;
        int kc = rem >> 10, rem2 = rem & 1023;
        int q = rem2 >> 6, lane = rem2 & 63;
        const float* W = (which == 0) ? eW1 : (which == 1) ? (eW1 + 512 * 256) : nW1;
        int n = (q >> 2) * 64 + (q & 3) * 16 + (lane & 15);
        int kbase = kc * 32 + (lane >> 4) * 8;
        u16x8 o;
#pragma unroll
        for (int jj = 0; jj < 8; ++jj)
            o[jj] = f2bf(W[(size_t)(kbase + jj) * 256 + n]);
        *(u16x8*)&w3c[(size_t)T * 8] = o;
        return;
    }
    if (y >= 3) {                 // e2s / c1s chunked (K=256)
        if (blockIdx.x >= 32) return;
        const float* W = (y == 3) ? eW2 : cW1;
        u16* dst = (y == 3) ? e2s : c1s;
        int T = blockIdx.x * 256 + threadIdx.x;      // [0, 8192)
        int kc = T >> 10, rem = T & 1023;
        int q = rem >> 6, lane = rem & 63;
        int n = (q >> 2) * 64 + (q & 3) * 16 + (lane & 15);
        int kbase = kc * 32 + (lane >> 4) * 8;
        u16x8 o;
#pragma unroll
        for (int jj = 0; jj < 8; ++jj)
            o[jj] = f2bf(W[(size_t)(kbase + jj) * 256 + n]);
        *(u16x8*)&dst[(size_t)T * 8] = o;
        return;
    }
    const float* src; u16* dstp; int Ks, Kd;
    switch (y) {
        case 0: src = eW1 + 1024 * 256;  dstp = e1pt; Ks = 52;  Kd = 64;  break;
        case 1: src = nW1 + 512 * 256;   dstp = n1t;  Ks = 256; Kd = 256; break;
        default: src = nW2;              dstp = n2t;  Ks = 256; Kd = 256; break;
    }
    int idx = blockIdx.x * 256 + threadIdx.x;
    if (idx < 256 * Kd) {
        int n = idx / Kd, k = idx - n * Kd;
        dstp[idx] = (k < Ks) ? f2bf(src[(size_t)k * 256 + n]) : (u16)0;
    }
}

__global__ __launch_bounds__(256) void conv_h(const float* __restrict__ h, u16* __restrict__ hb)
{
    size_t base = ((size_t)blockIdx.x * 256 + threadIdx.x) * 8;
    int row = (int)(base >> 9);
    u16x8 o;
    if (row < N_NODES) {
        const float4 f0 = *(const float4*)&h[base];
        const float4 f1 = *(const float4*)&h[base + 4];
        o[0] = f2bf(f0.x); o[1] = f2bf(f0.y); o[2] = f2bf(f0.z); o[3] = f2bf(f0.w);
        o[4] = f2bf(f1.x); o[5] = f2bf(f1.y); o[6] = f2bf(f1.z); o[7] = f2bf(f1.w);
    } else {
        o = (u16x8)0;
    }
    *(u16x8*)&hb[base] = o;
}

// eattr (f32 [E][51]) -> attrb (bf16 [E][64], zero-padded)
__global__ __launch_bounds__(256) void conv_attr(const float* __restrict__ eattr,
                                                 u16* __restrict__ attrb)
{
    int T = blockIdx.x * 256 + threadIdx.x;          // [0, E*8)
    int row = T >> 3, ch = T & 7;
    const float* src = eattr + (size_t)row * 51 + ch * 8;
    u16x8 o;
#pragma unroll
    for (int t = 0; t < 8; ++t) {
        int kk = ch * 8 + t;
        o[t] = (kk < 51) ? f2bf(src[t]) : (u16)0;
    }
    *(u16x8*)&attrb[(size_t)T * 8] = o;
}

// ---------------------------------------------------------------------------
__global__ __launch_bounds__(256) void hist_kernel(const int* __restrict__ row,
                                                   int* __restrict__ hist)
{
    int e = blockIdx.x * 256 + threadIdx.x;
    if (e < E_EDGES) atomicAdd(&hist[row[e]], 1);
}

#define SCAN_PER 40
__global__ __launch_bounds__(256) void scan_kernel(const int* __restrict__ hist,
                                                   int* __restrict__ rowptr)
{
    __shared__ int a[256];
    const int t = threadIdx.x;
    const int base = t * SCAN_PER;
    int s = 0;
    for (int i = 0; i < SCAN_PER; ++i) {
        int b = base + i;
        if (b < N_PAD) s += hist[b];
    }
    a[t] = s;
    __syncthreads();
    for (int off = 1; off < 256; off <<= 1) {
        int v = (t >= off) ? a[t - off] : 0;
        __syncthreads();
        a[t] += v;
        __syncthreads();
    }
    int run = a[t] - s;
    for (int i = 0; i < SCAN_PER; ++i) {
        int b = base + i;
        if (b < N_PAD) { rowptr[b] = run; run += hist[b]; }
    }
    if (t == 255) rowptr[N_PAD] = a[255];
}

__global__ __launch_bounds__(256) void scatter_kernel(const int* __restrict__ row,
                                                      const int* __restrict__ rowptr,
                                                      int* __restrict__ cnt,
                                                      int* __restrict__ eorder)
{
    int e = blockIdx.x * 256 + threadIdx.x;
    if (e < E_EDGES) {
        int r = row[e];
        int p = rowptr[r] + atomicAdd(&cnt[r], 1);
        eorder[p] = e;
    }
}

// ---------------------------------------------------------------------------
// precompute_X v2: h panel staged via pre-swizzled global_load_lds (1KB rows,
// XOR granule swizzle); W streamed via wave-private half-chunk double-buffer
// with counted vmcnt (e2-proven pipeline). Zero barriers in K-loop.
// ---------------------------------------------------------------------------
__global__ __launch_bounds__(256) void precompute_X(
    const u16* __restrict__ hb, const u16* __restrict__ w3c, u16* __restrict__ Xb)
{
    __shared__ u16 hs[32 * 512];      // 32 KB swizzled h panel
    __shared__ u16 ldsB[2][4096];     // 16 KB half-chunk double buffer

    const int n0b = blockIdx.x * 32;
    const int which = blockIdx.y;
    const int j = threadIdx.x, w = j >> 6, lane = j & 63;
    const int ml = lane & 15, g = lane >> 4;
    const int n0 = w * 64;
    const u16* Wc = w3c + (size_t)which * 16 * 8192;
    const f32x4 z = {0.f, 0.f, 0.f, 0.f};

    // stage hs: dest linear, source granule pre-swizzled (c ^ (row&7))
#pragma unroll
    for (int i = 0; i < 8; ++i) {
        int d = i * 256 + j;
        int row = d >> 6, c = d & 63;
        const u16* src = &hb[(size_t)(n0b + row) * 512 + (c ^ (row & 7)) * 8];
        __builtin_amdgcn_global_load_lds((gu32*)src, (lu32*)&hs[d * 8], 16, 0, 0);
    }
    // B half-chunk 0
#pragma unroll
    for (int i = 0; i < 2; ++i) {
        const u16* src = Wc + (size_t)((4 * w + i) * 512 + lane * 8);
        __builtin_amdgcn_global_load_lds((gu32*)src,
            (lu32*)&ldsB[0][w * 1024 + i * 512 + lane * 8], 16, 0, 0);
    }
    asm volatile("s_waitcnt vmcnt(2) lgkmcnt(0)" ::: "memory");
    __builtin_amdgcn_s_barrier();

    f32x4 acc[2][4];
#pragma unroll
    for (int mt = 0; mt < 2; ++mt)
#pragma unroll
        for (int nt = 0; nt < 4; ++nt) acc[mt][nt] = z;

    for (int hc = 0; hc < 32; ++hc) {
        int kc = hc >> 1, h = hc & 1;
        if (hc < 31) {
            int kc1 = (hc + 1) >> 1, h1 = (hc + 1) & 1;
#pragma unroll
            for (int i = 0; i < 2; ++i) {
                const u16* src = Wc + (size_t)kc1 * 8192 + (4 * w + 2 * h1 + i) * 512 + lane * 8;
                __builtin_amdgcn_global_load_lds((gu32*)src,
                    (lu32*)&ldsB[(hc + 1) & 1][w * 1024 + i * 512 + lane * 8], 16, 0, 0);
            }
            asm volatile("s_waitcnt vmcnt(2)" ::: "memory");
        } else {
            asm volatile("s_waitcnt vmcnt(0)" ::: "memory");
        }
        __builtin_amdgcn_sched_barrier(0);
        bf16x8 a0 = *(const bf16x8*)((const char*)hs + ((ml * 1024 + (kc * 32 + g * 8) * 2) ^ ((ml & 7) << 4)));
        bf16x8 a1 = *(const bf16x8*)((const char*)hs + (((16 + ml) * 1024 + (kc * 32 + g * 8) * 2) ^ ((ml & 7) << 4)));
#pragma unroll
        for (int i = 0; i < 2; ++i) {
            int nt = 2 * h + i;
            bf16x8 b = *(const bf16x8*)&ldsB[hc & 1][w * 1024 + i * 512 + lane * 8];
            acc[0][nt] = mfma16(a0, b, acc[0][nt]);
            acc[1][nt] = mfma16(a1, b, acc[1][nt]);
        }
    }
#pragma unroll
    for (int mt = 0; mt < 2; ++mt)
#pragma unroll
        for (int nt = 0; nt < 4; ++nt) {
            int col = n0 + nt * 16 + ml;
#pragma unroll
            for (int i = 0; i < 4; ++i) {
                int row = n0b + mt * 16 + g * 4 + i;
                Xb[(size_t)row * 768 + which * 256 + col] = f2bf(acc[mt][nt][i]);
            }
        }
}

// ---------------------------------------------------------------------------
// e1: gather + attr (vectorized via attrb) + stage-1 MFMA -> act1 tiles in HBM
// ---------------------------------------------------------------------------
__global__ __launch_bounds__(256) void e1_kernel(
    const u16* __restrict__ Xb, const float* __restrict__ pos,
    const int* __restrict__ eidx, const u16* __restrict__ attrb,
    const int* __restrict__ eorder,
    const u16* __restrict__ e1pt, const float* __restrict__ eb1,
    int t0, u16* __restrict__ act1s,
    int* __restrict__ ri_sorted, float* __restrict__ difp)
{
    __shared__ u16 attr[EB * 64];     // 4 KB swizzled
    __shared__ u16 bufA[EB * 256];    // 16 KB, xsum -> act1 in place
    __shared__ int ri_s[EB], ci_s[EB], es_s[EB];
    __shared__ float rad_s[EB];

    const int j = threadIdx.x, w = j >> 6, lane = j & 63;
    const int ml = lane & 15, g = lane >> 4;
    const int n0 = w * 64;
    const f32x4 z = {0.f, 0.f, 0.f, 0.f};

    const int wg = xcd_swz(blockIdx.x, gridDim.x);
    const int e0 = (t0 + wg) * EB;

    if (j < EB) {
        int e = eorder[e0 + j];
        es_s[j] = e;
        int r = eidx[e], c = eidx[E_EDGES + e];
        ri_s[j] = r; ci_s[j] = c;
        ri_sorted[e0 + j] = r;
        float dx = pos[r * 3 + 0] - pos[c * 3 + 0];
        float dy = pos[r * 3 + 1] - pos[c * 3 + 1];
        float dz = pos[r * 3 + 2] - pos[c * 3 + 2];
        difp[e0 + j] = dx;
        difp[E_EDGES + e0 + j] = dy;
        difp[2 * E_EDGES + e0 + j] = dz;
        rad_s[j] = sqrtf(dx * dx + dy * dy + dz * dz) + 1e-8f;
    }
    __syncthreads();

    // gather xsum = Xr + Xc -> bufA (swizzled)
#pragma unroll
    for (int t = 0; t < 4; ++t) {
        int li = t * 256 + j;
        int e = li >> 5, c = li & 31;
        const u16x8 xr = *(const u16x8*)&Xb[(size_t)ri_s[e] * 768 + c * 8];
        const u16x8 xc = *(const u16x8*)&Xb[(size_t)ci_s[e] * 768 + 256 + c * 8];
        u32x4 o;
#pragma unroll
        for (int k = 0; k < 4; ++k)
            o[k] = cvtpk(bf2f(xr[2 * k]) + bf2f(xc[2 * k]),
                         bf2f(xr[2 * k + 1]) + bf2f(xc[2 * k + 1]));
        *(u32x4*)((char*)bufA + ((e * 512 + c * 16) ^ ((e & 7) << 4))) = o;
    }
    // attr staging: one u16x8 per thread (row = j>>3, granule = j&7)
    {
        int row = j >> 3, g8 = j & 7;
        u16x8 o = *(const u16x8*)&attrb[(size_t)es_s[row] * 64 + g8 * 8];
        if (g8 == 6) o[3] = f2bf(rad_s[row]);     // col 51 = radial
        int byte = (row * 128 + g8 * 16) ^ ((row & 7) << 4);
        *(u16x8*)((char*)attr + byte) = o;
    }
    __syncthreads();

    f32x4 acc[2][4];
#pragma unroll
    for (int mt = 0; mt < 2; ++mt)
#pragma unroll
        for (int nt = 0; nt < 4; ++nt) acc[mt][nt] = z;
#pragma unroll
    for (int kc = 0; kc < 2; ++kc) {
        bf16x8 a0 = *(const bf16x8*)((const char*)attr + ((ml * 128 + (kc * 32 + g * 8) * 2) ^ ((ml & 7) << 4)));
        bf16x8 a1 = *(const bf16x8*)((const char*)attr + (((16 + ml) * 128 + (kc * 32 + g * 8) * 2) ^ ((ml & 7) << 4)));
#pragma unroll
        for (int nt = 0; nt < 4; ++nt) {
            bf16x8 b = *(const bf16x8*)&e1pt[(size_t)(n0 + nt * 16 + ml) * 64 + kc * 32 + g * 8];
            acc[0][nt] = mfma16(a0, b, acc[0][nt]);
            acc[1][nt] = mfma16(a1, b, acc[1][nt]);
        }
    }
#pragma unroll
    for (int nt = 0; nt < 4; ++nt) {
        int col = n0 + nt * 16 + ml;
        float b1 = eb1[col];
#pragma unroll
        for (int mt = 0; mt < 2; ++mt)
#pragma unroll
            for (int i = 0; i < 4; ++i) {
                int row = mt * 16 + g * 4 + i;
                int off = actb(row, col) >> 1;
                float v = acc[mt][nt][i] + b1 + bf2f(bufA[off]);
                bufA[off] = f2bf(silu_f(v));
            }
    }
    __syncthreads();

    // coalesced copy of swizzled tile image to HBM
    const size_t obase = (size_t)wg * (EB * 256);
#pragma unroll
    for (int i = 0; i < 4; ++i) {
        int li = i * 256 + j;
        *(u16x8*)&act1s[obase + (size_t)li * 8] = *(const u16x8*)&bufA[li * 8];
    }
}

// ---------------------------------------------------------------------------
// e2 v3 (R13 proven): act tile via global_load_lds; B wave-private half-chunk
// double-buffer, counted vmcnt, zero barriers in K-loops.
// ---------------------------------------------------------------------------
__global__ __launch_bounds__(256) void e2_kernel(
    const u16* __restrict__ act1s,
    const u16* __restrict__ e2s, const float* __restrict__ eb2,
    const u16* __restrict__ c1s, const float* __restrict__ cb1,
    const float* __restrict__ cW2,
    const int* __restrict__ ri_sorted, const float* __restrict__ difp,
    int t0, float* __restrict__ agg_node, float* __restrict__ agg_coord)
{
    __shared__ u16 bufA[EB * 256];    // 16 KB act1 -> act2 in place
    __shared__ u16 ldsB[2][4096];     // 16 KB half-chunk double buffer
    __shared__ int ri_s[EB];
    __shared__ float red[EB * 4];

    const int j = threadIdx.x, w = j >> 6, lane = j & 63;
    const int ml = lane & 15, g = lane >> 4;
    const int n0 = w * 64;
    const f32x4 z = {0.f, 0.f, 0.f, 0.f};

    const int wg = xcd_swz(blockIdx.x, gridDim.x);
    const int e0 = (t0 + wg) * EB;

    // stage act tile (linear; image pre-swizzled by e1) + e2s half-chunk 0
    {
        const size_t gbase = (size_t)wg * (EB * 256);
#pragma unroll
        for (int i = 0; i < 4; ++i) {
            const u16* src = act1s + gbase + (size_t)(i * 256 + j) * 8;
            u16* dst = &bufA[(i * 256 + j) * 8];
            __builtin_amdgcn_global_load_lds((gu32*)src, (lu32*)dst, 16, 0, 0);
        }
#pragma unroll
        for (int i = 0; i < 2; ++i) {
            const u16* src = e2s + (size_t)((4 * w + i) * 512 + lane * 8);
            u16* dst = &ldsB[0][w * 1024 + i * 512 + lane * 8];
            __builtin_amdgcn_global_load_lds((gu32*)src, (lu32*)dst, 16, 0, 0);
        }
    }
    if (j < EB) ri_s[j] = ri_sorted[e0 + j];
    asm volatile("s_waitcnt vmcnt(2) lgkmcnt(0)" ::: "memory");
    __builtin_amdgcn_s_barrier();

    f32x4 acc[2][4];

    // ---- stage 2: barrier-free K-loop, 16 half-chunks, counted vmcnt
#pragma unroll
    for (int mt = 0; mt < 2; ++mt)
#pragma unroll
        for (int nt = 0; nt < 4; ++nt) acc[mt][nt] = z;
    for (int hc = 0; hc < 16; ++hc) {
        int kc = hc >> 1, h = hc & 1;
        if (hc < 15) {
            int kc1 = (hc + 1) >> 1, h1 = (hc + 1) & 1;
#pragma unroll
            for (int i = 0; i < 2; ++i) {
                const u16* src = e2s + (size_t)kc1 * 8192 + (4 * w + 2 * h1 + i) * 512 + lane * 8;
                u16* dst = &ldsB[(hc + 1) & 1][w * 1024 + i * 512 + lane * 8];
                __builtin_amdgcn_global_load_lds((gu32*)src, (lu32*)dst, 16, 0, 0);
            }
            asm volatile("s_waitcnt vmcnt(2)" ::: "memory");
        } else {
            asm volatile("s_waitcnt vmcnt(0)" ::: "memory");
        }
        __builtin_amdgcn_sched_barrier(0);
        bf16x8 a0 = *(const bf16x8*)((const char*)bufA + actb(ml, kc * 32 + g * 8));
        bf16x8 a1 = *(const bf16x8*)((const char*)bufA + actb(16 + ml, kc * 32 + g * 8));
#pragma unroll
        for (int i = 0; i < 2; ++i) {
            int nt = 2 * h + i;
            bf16x8 b = *(const bf16x8*)&ldsB[hc & 1][w * 1024 + i * 512 + lane * 8];
            acc[0][nt] = mfma16(a0, b, acc[0][nt]);
            acc[1][nt] = mfma16(a1, b, acc[1][nt]);
        }
    }
    asm volatile("s_waitcnt lgkmcnt(0)" ::: "memory");
    __builtin_amdgcn_s_barrier();                 // all act1 reads done

    // prefetch c1s half-chunk 0 (overlaps epilogue)
#pragma unroll
    for (int i = 0; i < 2; ++i) {
        const u16* src = c1s + (size_t)((4 * w + i) * 512 + lane * 8);
        u16* dst = &ldsB[0][w * 1024 + i * 512 + lane * 8];
        __builtin_amdgcn_global_load_lds((gu32*)src, (lu32*)dst, 16, 0, 0);
    }

    // stage-2 epilogue: act2 = silu(acc + b2) in place
#pragma unroll
    for (int nt = 0; nt < 4; ++nt) {
        int col = n0 + nt * 16 + ml;
        float b2 = eb2[col];
#pragma unroll
        for (int mt = 0; mt < 2; ++mt)
#pragma unroll
            for (int i = 0; i < 4; ++i) {
                int row = mt * 16 + g * 4 + i;
                bufA[actb(row, col) >> 1] = f2bf(silu_f(acc[mt][nt][i] + b2));
            }
    }
    asm volatile("s_waitcnt lgkmcnt(0)" ::: "memory");
    __builtin_amdgcn_s_barrier();                 // act2 visible

    // ---- stage 3: same barrier-free K-loop with c1s
#pragma unroll
    for (int mt = 0; mt < 2; ++mt)
#pragma unroll
        for (int nt = 0; nt < 4; ++nt) acc[mt][nt] = z;
    for (int hc = 0; hc < 16; ++hc) {
        int kc = hc >> 1, h = hc & 1;
        if (hc < 15) {
            int kc1 = (hc + 1) >> 1, h1 = (hc + 1) & 1;
#pragma unroll
            for (int i = 0; i < 2; ++i) {
                const u16* src = c1s + (size_t)kc1 * 8192 + (4 * w + 2 * h1 + i) * 512 + lane * 8;
                u16* dst = &ldsB[(hc + 1) & 1][w * 1024 + i * 512 + lane * 8];
                __builtin_amdgcn_global_load_lds((gu32*)src, (lu32*)dst, 16, 0, 0);
            }
            asm volatile("s_waitcnt vmcnt(2)" ::: "memory");
        } else {
            asm volatile("s_waitcnt vmcnt(0)" ::: "memory");
        }
        __builtin_amdgcn_sched_barrier(0);
        bf16x8 a0 = *(const bf16x8*)((const char*)bufA + actb(ml, kc * 32 + g * 8));
        bf16x8 a1 = *(const bf16x8*)((const char*)bufA + actb(16 + ml, kc * 32 + g * 8));
#pragma unroll
        for (int i = 0; i < 2; ++i) {
            int nt = 2 * h + i;
            bf16x8 b = *(const bf16x8*)&ldsB[hc & 1][w * 1024 + i * 512 + lane * 8];
            acc[0][nt] = mfma16(a0, b, acc[0][nt]);
            acc[1][nt] = mfma16(a1, b, acc[1][nt]);
        }
    }

    // ---- p-epilogue first (consumes acc): u = clip((silu(c + cb1)) . cW2)
    float p[2][4] = {{0.f, 0.f, 0.f, 0.f}, {0.f, 0.f, 0.f, 0.f}};
#pragma unroll
    for (int nt = 0; nt < 4; ++nt) {
        int col = n0 + nt * 16 + ml;
        float b3 = cb1[col];
        float w2 = cW2[col];
#pragma unroll
        for (int mt = 0; mt < 2; ++mt)
#pragma unroll
            for (int i = 0; i < 4; ++i)
                p[mt][i] += silu_f(acc[mt][nt][i] + b3) * w2;
    }
#pragma unroll
    for (int mt = 0; mt < 2; ++mt)
#pragma unroll
        for (int i = 0; i < 4; ++i) {
            float v = p[mt][i];
            v += __shfl_xor(v, 1);
            v += __shfl_xor(v, 2);
            v += __shfl_xor(v, 4);
            v += __shfl_xor(v, 8);
            p[mt][i] = v;
        }
    if (ml == 0) {
#pragma unroll
        for (int mt = 0; mt < 2; ++mt)
#pragma unroll
            for (int i = 0; i < 4; ++i)
                red[(mt * 16 + g * 4 + i) * 4 + w] = p[mt][i];
    }
    __syncthreads();
    if (j < EB) {
        float u = red[j * 4 + 0] + red[j * 4 + 1] + red[j * 4 + 2] + red[j * 4 + 3];
        u = fminf(fmaxf(u, -1.f), 1.f);
        int rr = ri_s[j];
        atomicAdd(&agg_coord[(size_t)rr * 3 + 0], u * difp[e0 + j]);
        atomicAdd(&agg_coord[(size_t)rr * 3 + 1], u * difp[E_EDGES + e0 + j]);
        atomicAdd(&agg_coord[(size_t)rr * 3 + 2], u * difp[2 * E_EDGES + e0 + j]);
    }

    // ---- RL-agg: preload act2 column to registers, then run loop on regs
    {
        float vreg[EB];
#pragma unroll
        for (int m = 0; m < EB; ++m)
            vreg[m] = bf2f(bufA[actb(m, j) >> 1]);
        int cur = ri_s[0];
        float s = vreg[0];
#pragma unroll
        for (int m = 1; m < EB; ++m) {
            int r = ri_s[m];
            if (r != cur) {
                atomicAdd(&agg_node[(size_t)cur * 256 + j], s);
                s = 0.f; cur = r;
            }
            s += vreg[m];
        }
        atomicAdd(&agg_node[(size_t)cur * 256 + j], s);
    }
}

// ---------------------------------------------------------------------------
__global__ __launch_bounds__(256) void node_kernel(
    const u16* __restrict__ Xb, const float* __restrict__ agg_node,
    const float* __restrict__ agg_coord, const float* __restrict__ pos,
    const u16* __restrict__ n1t, const float* __restrict__ nb1,
    const u16* __restrict__ n2t, const float* __restrict__ nb2,
    float* __restrict__ out)
{
    __shared__ u16 act1[32 * 256];
    __shared__ u16 act2[32 * 256];
    const int n0b = blockIdx.x * 32;
    const int j = threadIdx.x, wv = j >> 6, lane = j & 63;
    const int ml = lane & 15, g = lane >> 4;
    const int n0 = wv * 64;
    const f32x4 z = {0.f, 0.f, 0.f, 0.f};

    for (int li = j; li < 32 * 256; li += 256) {
        int r = li >> 8, c = li & 255;
        act1[actb(r, c) >> 1] = f2bf(agg_node[(size_t)(n0b + r) * 256 + c]);
    }
    __syncthreads();

    f32x4 acc[2][4];
#pragma unroll
    for (int mt = 0; mt < 2; ++mt)
#pragma unroll
        for (int nt = 0; nt < 4; ++nt) acc[mt][nt] = z;
    for (int kc = 0; kc < 8; ++kc) {
        bf16x8 a0 = *(const bf16x8*)((const char*)act1 + actb(ml, kc * 32 + g * 8));
        bf16x8 a1 = *(const bf16x8*)((const char*)act1 + actb(16 + ml, kc * 32 + g * 8));
#pragma unroll
        for (int nt = 0; nt < 4; ++nt) {
            bf16x8 b = *(const bf16x8*)&n1t[(size_t)(n0 + nt * 16 + ml) * 256 + kc * 32 + g * 8];
            acc[0][nt] = mfma16(a0, b, acc[0][nt]);
            acc[1][nt] = mfma16(a1, b, acc[1][nt]);
        }
    }
#pragma unroll
    for (int mt = 0; mt < 2; ++mt)
#pragma unroll
        for (int nt = 0; nt < 4; ++nt) {
            int col = n0 + nt * 16 + ml;
            float b1 = nb1[col];
#pragma unroll
            for (int i = 0; i < 4; ++i) {
                int m = mt * 16 + g * 4 + i;
                float v = acc[mt][nt][i] + b1 + bf2f(Xb[(size_t)(n0b + m) * 768 + 512 + col]);
                act2[actb(m, col) >> 1] = f2bf(silu_f(v));
            }
        }
    __syncthreads();
#pragma unroll
    for (int mt = 0; mt < 2; ++mt)
#pragma unroll
        for (int nt = 0; nt < 4; ++nt) acc[mt][nt] = z;
    for (int kc = 0; kc < 8; ++kc) {
        bf16x8 a0 = *(const bf16x8*)((const char*)act2 + actb(ml, kc * 32 + g * 8));
        bf16x8 a1 = *(const bf16x8*)((const char*)act2 + actb(16 + ml, kc * 32 + g * 8));
#pragma unroll
        for (int nt = 0; nt < 4; ++nt) {
            bf16x8 b = *(const bf16x8*)&n2t[(size_t)(n0 + nt * 16 + ml) * 256 + kc * 32 + g * 8];
            acc[0][nt] = mfma16(a0, b, acc[0][nt]);
            acc[1][nt] = mfma16(a1, b, acc[1][nt]);
        }
    }
#pragma unroll
    for (int mt = 0; mt < 2; ++mt)
#pragma unroll
        for (int nt = 0; nt < 4; ++nt) {
            int col = n0 + nt * 16 + ml;
            float b2 = nb2[col];
#pragma unroll
            for (int i = 0; i < 4; ++i) {
                int row = n0b + mt * 16 + g * 4 + i;
                if (row < N_NODES)
                    out[(size_t)row * 256 + col] = acc[mt][nt][i] + b2;
            }
        }
    if (j < 96) {
        int idx = n0b * 3 + j;
        if (idx < N_NODES * 3)
            out[(size_t)N_NODES * 256 + idx] = pos[idx] + agg_coord[idx];
    }
}

// ---------------------------------------------------------------------------
extern "C" void kernel_launch(void* const* d_in, const int* in_sizes, int n_in,
                              void* d_out, int out_size, void* d_ws, size_t ws_size,
                              hipStream_t stream)
{
    (void)in_sizes; (void)n_in; (void)out_size;
    const float* h     = (const float*)d_in[0];
    const int*   eidx  = (const int*)d_in[1];
    const float* eattr = (const float*)d_in[2];
    const float* pos   = (const float*)d_in[3];
    const float* eW1   = (const float*)d_in[4];
    const float* eb1   = (const float*)d_in[5];
    const float* eW2   = (const float*)d_in[6];
    const float* eb2   = (const float*)d_in[7];
    const float* cW1   = (const float*)d_in[8];
    const float* cb1   = (const float*)d_in[9];
    const float* cW2   = (const float*)d_in[10];
    const float* nW1   = (const float*)d_in[11];
    const float* nb1   = (const float*)d_in[12];
    const float* nW2   = (const float*)d_in[13];
    const float* nb2   = (const float*)d_in[14];
    float* out = (float*)d_out;

    u16* Xb   = (u16*)d_ws;                                  // N_PAD*768 bf16
    u16* hb   = Xb + (size_t)N_PAD * 768;                    // N_PAD*512
    u16* e1pt = hb + (size_t)N_PAD * 512;                    // 256*64
    u16* n1t  = e1pt + 256 * 64;                             // 256*256
    u16* n2t  = n1t + 256 * 256;                             // 256*256
    u16* e2s  = n2t + 256 * 256;                             // 65536 u16
    u16* c1s  = e2s + 65536;                                 // 65536 u16
    u16* w3c  = c1s + 65536;                                 // 3*16*8192 u16
    u16* attrb = w3c + 3 * 16 * 8192;                        // E*64 u16
    float* agg_node  = (float*)(attrb + (size_t)E_EDGES * 64);  // N_PAD*256 f32
    float* agg_coord = agg_node + (size_t)N_PAD * 256;       // N_PAD*3
    int* hist   = (int*)(agg_coord + (size_t)N_PAD * 3);     // N_PAD
    int* cnt    = hist + N_PAD;                              // N_PAD
    int* rowptr = cnt + N_PAD;                               // N_PAD+1
    int* eorder = rowptr + N_PAD + 1;                        // E
    int* ri_sorted = eorder + E_EDGES;                       // E
    float* difp = (float*)(ri_sorted + E_EDGES);             // 3*E
    char* wend = (char*)(difp + (size_t)3 * E_EDGES);
    u16* act1s = (u16*)(((uintptr_t)wend + 255) & ~(uintptr_t)255);

    size_t avail = ws_size - (size_t)((char*)act1s - (char*)d_ws);
    int tiles_cap = (int)(avail / (EB * 256 * sizeof(u16)));
    int chunk = tiles_cap < NTILES ? tiles_cap : NTILES;
    if (chunk < 1) chunk = 1;

    hipMemsetAsync(agg_node, 0, (size_t)N_PAD * 259 * sizeof(float), stream);
    hipMemsetAsync(hist, 0, (size_t)2 * N_PAD * sizeof(int), stream);

    prep_weights<<<dim3(512, 6), 256, 0, stream>>>(eW1, eW2, cW1, nW1, nW2,
                                                   e1pt, n1t, n2t, e2s, c1s, w3c);
    conv_h<<<(N_PAD * 512 / 8) / 256, 256, 0, stream>>>(h, hb);
    conv_attr<<<(E_EDGES * 8) / 256, 256, 0, stream>>>(eattr, attrb);

    hist_kernel<<<(E_EDGES + 255) / 256, 256, 0, stream>>>(eidx, hist);
    scan_kernel<<<1, 256, 0, stream>>>(hist, rowptr);
    scatter_kernel<<<(E_EDGES + 255) / 256, 256, 0, stream>>>(eidx, rowptr, cnt, eorder);

    precompute_X<<<dim3(N_PAD / 32, 3), 256, 0, stream>>>(hb, w3c, Xb);

    for (int c = 0; c < NTILES; c += chunk) {
        int g = (NTILES - c) < chunk ? (NTILES - c) : chunk;
        e1_kernel<<<g, 256, 0, stream>>>(Xb, pos, eidx, attrb, eorder,
                                         e1pt, eb1, c, act1s, ri_sorted, difp);
        e2_kernel<<<g, 256, 0, stream>>>(act1s, e2s, eb2, c1s, cb1, cW2,
                                         ri_sorted, difp, c, agg_node, agg_coord);
    }

    node_kernel<<<N_PAD / 32, 256, 0, stream>>>(
        Xb, agg_node, agg_coord, pos, n1t, nb1, n2t, nb2, out);
}